// Round 1
// baseline (206.733 us; speedup 1.0000x reference)
//
#include <hip/hip_runtime.h>
#include <hip/hip_bf16.h>
#include <math.h>

#define BATCH 8192
#define FEAT  256
#define NCLS  1000

// ---------------------------------------------------------------------------
// ws layout (bytes):
//   mag    [0,     32768)   8192 f32   ||x_i||^2
//   cmag   [32768, 36768)   1000 f32   2*||c_j||^2
//   counts [36864, 40864)   1000 int   per-label histogram
//   offs   [40960, 44960)   1000 int   exclusive scan
//   cursor [45056, 49056)   1000 int   scatter cursors
//   idx    [49152, 81920)   8192 int   sample indices grouped by label
//   scal   [81920, 81928)   2 u32      [0]=intra max bits, [1]=inter min bits
// Total ~82 KB. Everything rewritten every call (ws is poisoned to 0xAA).
// ---------------------------------------------------------------------------

__global__ void k_init(int* __restrict__ counts, unsigned int* __restrict__ scal) {
    int t = blockIdx.x * blockDim.x + threadIdx.x;
    if (t < NCLS) counts[t] = 0;
    if (t == 0) {
        // masked intra matrix always contains the diagonal (d clamped to 1e-12)
        scal[0] = __float_as_uint(1e-12f);  // running max (positive floats: uint cmp == float cmp)
        scal[1] = __float_as_uint(1e12f);   // running min (clip upper bound)
    }
}

// One wave (64 lanes) per row; rows [0,BATCH) are x, [BATCH,BATCH+NCLS) are centers.
// lane reads float4 at col lane*4 -> 64*4 = 256 = FEAT, fully coalesced.
__global__ void k_rownorm_hist(const float* __restrict__ x,
                               const float* __restrict__ centers,
                               const int* __restrict__ labels,
                               float* __restrict__ mag, float* __restrict__ cmag,
                               int* __restrict__ counts) {
    int wave = (blockIdx.x * blockDim.x + threadIdx.x) >> 6;
    int lane = threadIdx.x & 63;
    if (wave >= BATCH + NCLS) return;
    const float* row = (wave < BATCH) ? (x + (size_t)wave * FEAT)
                                      : (centers + (size_t)(wave - BATCH) * FEAT);
    float4 v = reinterpret_cast<const float4*>(row)[lane];
    float s = v.x * v.x + v.y * v.y + v.z * v.z + v.w * v.w;
    #pragma unroll
    for (int o = 32; o > 0; o >>= 1) s += __shfl_xor(s, o);
    if (lane == 0) {
        if (wave < BATCH) {
            mag[wave] = s;
            atomicAdd(&counts[labels[wave]], 1);
        } else {
            cmag[wave - BATCH] = 2.0f * s;
        }
    }
}

// Single-block Hillis-Steele exclusive scan over the 1000 counts.
__global__ void k_scan(const int* __restrict__ counts,
                       int* __restrict__ offs, int* __restrict__ cursor) {
    __shared__ int s[1024];
    int t = threadIdx.x;
    int v = (t < NCLS) ? counts[t] : 0;
    s[t] = v;
    __syncthreads();
    for (int o = 1; o < 1024; o <<= 1) {
        int add = (t >= o) ? s[t - o] : 0;
        __syncthreads();
        s[t] += add;
        __syncthreads();
    }
    if (t < NCLS) { int e = s[t] - v; offs[t] = e; cursor[t] = e; }
}

__global__ void k_scatter(const int* __restrict__ labels,
                          int* __restrict__ cursor, int* __restrict__ idx) {
    int i = blockIdx.x * blockDim.x + threadIdx.x;
    if (i < BATCH) {
        int pos = atomicAdd(&cursor[labels[i]], 1);
        idx[pos] = i;
    }
}

// One block (4 waves) per label; one wave per pair; 64 lanes split the 256-dim dot.
// Max over pairs is order-independent -> scatter order / atomic order don't matter.
__global__ void k_intra(const float* __restrict__ x, const float* __restrict__ mag,
                        const int* __restrict__ counts, const int* __restrict__ offs,
                        const int* __restrict__ idx, unsigned int* __restrict__ scal) {
    int l = blockIdx.x;
    int n = counts[l];
    if (n < 2) return;                // diagonal-only contribution (1e-12) is the init value
    int off  = offs[l];
    int wid  = threadIdx.x >> 6;
    int lane = threadIdx.x & 63;
    int npairs = n * (n - 1) / 2;
    float vmax = 0.0f;
    for (int p = wid; p < npairs; p += 4) {
        // unrank pair index p -> (a,b), a<b  (n is small, ~8-25; loop is cheap+uniform)
        int a = 0, rem = p;
        while (rem >= n - 1 - a) { rem -= n - 1 - a; ++a; }
        int b = a + 1 + rem;
        int ia = idx[off + a], ib = idx[off + b];
        float4 va = reinterpret_cast<const float4*>(x + (size_t)ia * FEAT)[lane];
        float4 vb = reinterpret_cast<const float4*>(x + (size_t)ib * FEAT)[lane];
        float s = va.x * vb.x + va.y * vb.y + va.z * vb.z + va.w * vb.w;
        #pragma unroll
        for (int o = 32; o > 0; o >>= 1) s += __shfl_xor(s, o);
        float d2 = mag[ia] + mag[ib] - 2.0f * s;
        float d  = sqrtf(fmaxf(d2, 0.0f));
        d = fminf(fmaxf(d, 1e-12f), 1e12f);
        vmax = fmaxf(vmax, d);
    }
    if (lane == 0 && vmax > 0.0f)
        atomicMax(scal + 0, __float_as_uint(vmax));
}

// 32x32 output tile per block, 256 threads, each thread 4 outputs.
// LDS tiles padded to 33 to break the 32-way bank conflict on B[cc][k].
__global__ __launch_bounds__(256) void k_inter(const float* __restrict__ c,
                                               const float* __restrict__ cmag,
                                               unsigned int* __restrict__ scal) {
    __shared__ float A[32][33];
    __shared__ float B[32][33];
    int i0 = blockIdx.y * 32;
    int j0 = blockIdx.x * 32;
    int t  = threadIdx.x;
    int r0 = t >> 5;   // 0..7
    int cc = t & 31;   // 0..31
    float acc[4] = {0.f, 0.f, 0.f, 0.f};
    for (int kk = 0; kk < FEAT; kk += 32) {
        for (int e = t; e < 32 * 32; e += 256) {
            int row = e >> 5, col = e & 31;
            int gi = i0 + row;
            int gj = j0 + row;
            A[row][col] = (gi < NCLS) ? c[(size_t)gi * FEAT + kk + col] : 0.0f;
            B[row][col] = (gj < NCLS) ? c[(size_t)gj * FEAT + kk + col] : 0.0f;
        }
        __syncthreads();
        #pragma unroll
        for (int k = 0; k < 32; ++k) {
            float bv = B[cc][k];
            acc[0] += A[r0     ][k] * bv;
            acc[1] += A[r0 +  8][k] * bv;
            acc[2] += A[r0 + 16][k] * bv;
            acc[3] += A[r0 + 24][k] * bv;
        }
        __syncthreads();
    }
    float lmin = 1e30f;
    int j = j0 + cc;
    if (j < NCLS) {
        float cm = cmag[j];
        #pragma unroll
        for (int q = 0; q < 4; ++q) {
            int i = i0 + r0 + q * 8;
            if (i < NCLS) {
                float v = cm - 2.0f * acc[q];
                v = fminf(fmaxf(v, 1e-12f), 1e12f);
                lmin = fminf(lmin, v);
            }
        }
    }
    #pragma unroll
    for (int o = 32; o > 0; o >>= 1) lmin = fminf(lmin, __shfl_xor(lmin, o));
    if ((t & 63) == 0) atomicMin(scal + 1, __float_as_uint(lmin));
}

// Replicate the reference's exact final arithmetic:
// top2 = [M, M] (symmetric matrix) -> loss_intra = 2/(1/M + 1/M)
__global__ void k_final(const unsigned int* __restrict__ scal, float* __restrict__ out) {
    float M = __uint_as_float(scal[0]);
    float r = 1.0f / M;
    float li = 2.0f / (r + r);
    float m = __uint_as_float(scal[1]);
    float linter = fminf(fmaxf(5.0f - m, 0.0f), 1e6f);
    out[0] = 1.0f * li + 1.0f * linter;   // ALPHA=BETA=1
}

extern "C" void kernel_launch(void* const* d_in, const int* in_sizes, int n_in,
                              void* d_out, int out_size, void* d_ws, size_t ws_size,
                              hipStream_t stream) {
    const float* x       = (const float*)d_in[0];
    const int*   labels  = (const int*)d_in[1];
    const float* centers = (const float*)d_in[2];

    char* ws = (char*)d_ws;
    float*        mag    = (float*)(ws);
    float*        cmag   = (float*)(ws + 32768);
    int*          counts = (int*)(ws + 36864);
    int*          offs   = (int*)(ws + 40960);
    int*          cursor = (int*)(ws + 45056);
    int*          idx    = (int*)(ws + 49152);
    unsigned int* scal   = (unsigned int*)(ws + 81920);
    float*        out    = (float*)d_out;

    k_init<<<4, 256, 0, stream>>>(counts, scal);

    int waves = BATCH + NCLS;                       // one wave per row
    k_rownorm_hist<<<(waves + 3) / 4, 256, 0, stream>>>(x, centers, labels,
                                                        mag, cmag, counts);

    k_scan<<<1, 1024, 0, stream>>>(counts, offs, cursor);

    k_scatter<<<(BATCH + 255) / 256, 256, 0, stream>>>(labels, cursor, idx);

    k_intra<<<NCLS, 256, 0, stream>>>(x, mag, counts, offs, idx, scal);

    dim3 g((NCLS + 31) / 32, (NCLS + 31) / 32);
    k_inter<<<g, 256, 0, stream>>>(centers, cmag, scal);

    k_final<<<1, 1, 0, stream>>>(scal, out);
}

// Round 2
// 156.919 us; speedup vs baseline: 1.3175x; 1.3175x over previous
//
#include <hip/hip_runtime.h>
#include <math.h>

#define BATCH 8192
#define FEAT  256
#define NCLS  1000

#define NINTER_BLKS 256            // 16x16 grid of 64x64 output tiles
#define TOTAL_BLKS  (NINTER_BLKS + NCLS)

// ---------------------------------------------------------------------------
// ws layout (bytes):
//   mag     [0,     32768)   8192 f32   ||x_i||^2
//   cmag    [32768, 36768)   1000 f32   2*||c_j||^2
//   counts  [36864, 40864)   1000 int   per-label histogram
//   offs    [40960, 44960)   1000 int   exclusive scan
//   cursor  [45056, 49056)   1000 int   scatter cursors
//   idx     [49152, 81920)   8192 int   sample indices grouped by label
//   scal    [81920, 81928)   2 u32      [0]=intra max bits, [1]=inter min bits
//   donecnt [81928, 81932)   1 u32      block completion counter for fused final
// Everything rewritten every call (ws is poisoned to 0xAA).
// ---------------------------------------------------------------------------

// One block: label histogram + exclusive scan (wave-shuffle) + scalar init.
__global__ __launch_bounds__(1024) void k_prep(const int* __restrict__ labels,
                                               int* __restrict__ counts,
                                               int* __restrict__ offs,
                                               int* __restrict__ cursor,
                                               unsigned int* __restrict__ scal,
                                               unsigned int* __restrict__ donecnt) {
    __shared__ int hist[NCLS];
    __shared__ int wsum[16];
    int t = threadIdx.x;
    if (t < NCLS) hist[t] = 0;
    __syncthreads();
    #pragma unroll
    for (int r = 0; r < BATCH / 1024; ++r)
        atomicAdd(&hist[labels[r * 1024 + t]], 1);
    __syncthreads();

    int lane = t & 63, w = t >> 6;
    int orig = (t < NCLS) ? hist[t] : 0;
    int v = orig;
    #pragma unroll
    for (int o = 1; o < 64; o <<= 1) {           // inclusive scan within wave
        int u = __shfl_up(v, o);
        if (lane >= o) v += u;
    }
    if (lane == 63) wsum[w] = v;
    __syncthreads();
    if (w == 0) {                                 // scan the 16 wave totals
        int s = (lane < 16) ? wsum[lane] : 0;
        #pragma unroll
        for (int o = 1; o < 16; o <<= 1) {
            int u = __shfl_up(s, o);
            if (lane >= o) s += u;
        }
        if (lane < 16) wsum[lane] = s;
    }
    __syncthreads();
    int excl = v + ((w > 0) ? wsum[w - 1] : 0) - orig;
    if (t < NCLS) { counts[t] = orig; offs[t] = excl; cursor[t] = excl; }
    if (t == 0) {
        scal[0] = __float_as_uint(1e-12f);  // intra running max (diag clamp floor)
        scal[1] = __float_as_uint(1e12f);   // inter running min (clip upper bound)
        *donecnt = 0u;
    }
}

// One wave per row; rows [0,BATCH) = x, [BATCH,BATCH+NCLS) = centers.
__global__ void k_rownorm(const float* __restrict__ x,
                          const float* __restrict__ centers,
                          float* __restrict__ mag, float* __restrict__ cmag) {
    int wave = (blockIdx.x * blockDim.x + threadIdx.x) >> 6;
    int lane = threadIdx.x & 63;
    if (wave >= BATCH + NCLS) return;
    const float* row = (wave < BATCH) ? (x + (size_t)wave * FEAT)
                                      : (centers + (size_t)(wave - BATCH) * FEAT);
    float4 v = reinterpret_cast<const float4*>(row)[lane];
    float s = v.x * v.x + v.y * v.y + v.z * v.z + v.w * v.w;
    #pragma unroll
    for (int o = 32; o > 0; o >>= 1) s += __shfl_xor(s, o);
    if (lane == 0) {
        if (wave < BATCH) mag[wave] = s;
        else              cmag[wave - BATCH] = 2.0f * s;
    }
}

__global__ void k_scatter(const int* __restrict__ labels,
                          int* __restrict__ cursor, int* __restrict__ idx) {
    int i = blockIdx.x * blockDim.x + threadIdx.x;
    if (i < BATCH) {
        int pos = atomicAdd(&cursor[labels[i]], 1);
        idx[pos] = i;
    }
}

// Fused: blocks [0,NINTER_BLKS) = inter GEMM tiles; [NINTER_BLKS,+NCLS) = intra
// per-label pair max; last block to finish combines the two scalars.
__global__ __launch_bounds__(256) void k_fused(const float* __restrict__ x,
                                               const float* __restrict__ centers,
                                               const float* __restrict__ mag,
                                               const float* __restrict__ cmag,
                                               const int* __restrict__ counts,
                                               const int* __restrict__ offs,
                                               const int* __restrict__ idx,
                                               unsigned int* __restrict__ scal,
                                               unsigned int* __restrict__ donecnt,
                                               float* __restrict__ out) {
    // k-major LDS tiles: [k][row], padded row length 68 (16B-aligned rows,
    // bank stride 68%32=4 -> 2-way max on the b128 reads = free).
    __shared__ float As[32][68];
    __shared__ float Bs[32][68];

    if (blockIdx.x < NINTER_BLKS) {
        // ---- inter: 64x64 f32 tile, 4x4 register blocking per thread ----
        int bi = blockIdx.x >> 4, bj = blockIdx.x & 15;
        int i0 = bi * 64, j0 = bj * 64;
        int t  = threadIdx.x;
        int tx = t & 15, ty = t >> 4;
        float acc[4][4] = {{0.f}};
        for (int kk = 0; kk < FEAT; kk += 32) {
            #pragma unroll
            for (int e = t; e < 512; e += 256) {
                int row = e >> 3, q = e & 7;
                int col = kk + q * 4;
                int gi = i0 + row, gj = j0 + row;
                float4 av = (gi < NCLS)
                    ? *reinterpret_cast<const float4*>(centers + (size_t)gi * FEAT + col)
                    : make_float4(0.f, 0.f, 0.f, 0.f);
                float4 bv = (gj < NCLS)
                    ? *reinterpret_cast<const float4*>(centers + (size_t)gj * FEAT + col)
                    : make_float4(0.f, 0.f, 0.f, 0.f);
                As[q * 4 + 0][row] = av.x; As[q * 4 + 1][row] = av.y;
                As[q * 4 + 2][row] = av.z; As[q * 4 + 3][row] = av.w;
                Bs[q * 4 + 0][row] = bv.x; Bs[q * 4 + 1][row] = bv.y;
                Bs[q * 4 + 2][row] = bv.z; Bs[q * 4 + 3][row] = bv.w;
            }
            __syncthreads();
            #pragma unroll
            for (int k = 0; k < 32; ++k) {     // sequential k: same rounding as before
                float4 a4 = *reinterpret_cast<float4*>(&As[k][ty * 4]);
                float4 b4 = *reinterpret_cast<float4*>(&Bs[k][tx * 4]);
                acc[0][0] += a4.x * b4.x; acc[0][1] += a4.x * b4.y;
                acc[0][2] += a4.x * b4.z; acc[0][3] += a4.x * b4.w;
                acc[1][0] += a4.y * b4.x; acc[1][1] += a4.y * b4.y;
                acc[1][2] += a4.y * b4.z; acc[1][3] += a4.y * b4.w;
                acc[2][0] += a4.z * b4.x; acc[2][1] += a4.z * b4.y;
                acc[2][2] += a4.z * b4.z; acc[2][3] += a4.z * b4.w;
                acc[3][0] += a4.w * b4.x; acc[3][1] += a4.w * b4.y;
                acc[3][2] += a4.w * b4.z; acc[3][3] += a4.w * b4.w;
            }
            __syncthreads();
        }
        float lmin = 1e30f;
        #pragma unroll
        for (int jj = 0; jj < 4; ++jj) {
            int j = j0 + tx * 4 + jj;
            if (j < NCLS) {
                float cm = cmag[j];
                #pragma unroll
                for (int ii = 0; ii < 4; ++ii) {
                    int i = i0 + ty * 4 + ii;
                    if (i < NCLS) {
                        float v = cm - 2.0f * acc[ii][jj];
                        v = fminf(fmaxf(v, 1e-12f), 1e12f);
                        lmin = fminf(lmin, v);
                    }
                }
            }
        }
        #pragma unroll
        for (int o = 32; o > 0; o >>= 1) lmin = fminf(lmin, __shfl_xor(lmin, o));
        if ((t & 63) == 0) atomicMin(scal + 1, __float_as_uint(lmin));
    } else {
        // ---- intra: one block per label, one wave per pair ----
        int l = blockIdx.x - NINTER_BLKS;
        int n = counts[l];
        if (n >= 2) {
            int off  = offs[l];
            int wid  = threadIdx.x >> 6;
            int lane = threadIdx.x & 63;
            int npairs = n * (n - 1) / 2;
            float vmax = 0.0f;
            for (int p = wid; p < npairs; p += 4) {
                int a = 0, rem = p;                 // unrank (wave-uniform, n small)
                while (rem >= n - 1 - a) { rem -= n - 1 - a; ++a; }
                int b = a + 1 + rem;
                int ia = idx[off + a], ib = idx[off + b];
                float4 va = reinterpret_cast<const float4*>(x + (size_t)ia * FEAT)[lane];
                float4 vb = reinterpret_cast<const float4*>(x + (size_t)ib * FEAT)[lane];
                float s = va.x * vb.x + va.y * vb.y + va.z * vb.z + va.w * vb.w;
                #pragma unroll
                for (int o = 32; o > 0; o >>= 1) s += __shfl_xor(s, o);
                float d2 = mag[ia] + mag[ib] - 2.0f * s;
                float d  = sqrtf(fmaxf(d2, 0.0f));
                d = fminf(fmaxf(d, 1e-12f), 1e12f);
                vmax = fmaxf(vmax, d);
            }
            if (lane == 0 && vmax > 0.0f)
                atomicMax(scal + 0, __float_as_uint(vmax));
        }
    }

    // ---- last-done block computes the final scalar (replaces k_final) ----
    __syncthreads();              // all this block's atomics are at L2 after this
    if (threadIdx.x == 0) {
        __threadfence();
        unsigned int done = atomicAdd(donecnt, 1u);
        if (done == TOTAL_BLKS - 1) {
            float M = __uint_as_float(atomicOr(scal + 0, 0u));
            float r = 1.0f / M;
            float li = 2.0f / (r + r);              // harmonic mean of [M, M] * 2
            float m = __uint_as_float(atomicOr(scal + 1, 0u));
            float linter = fminf(fmaxf(5.0f - m, 0.0f), 1e6f);
            out[0] = 1.0f * li + 1.0f * linter;     // ALPHA = BETA = 1
        }
    }
}

extern "C" void kernel_launch(void* const* d_in, const int* in_sizes, int n_in,
                              void* d_out, int out_size, void* d_ws, size_t ws_size,
                              hipStream_t stream) {
    const float* x       = (const float*)d_in[0];
    const int*   labels  = (const int*)d_in[1];
    const float* centers = (const float*)d_in[2];

    char* ws = (char*)d_ws;
    float*        mag     = (float*)(ws);
    float*        cmag    = (float*)(ws + 32768);
    int*          counts  = (int*)(ws + 36864);
    int*          offs    = (int*)(ws + 40960);
    int*          cursor  = (int*)(ws + 45056);
    int*          idx     = (int*)(ws + 49152);
    unsigned int* scal    = (unsigned int*)(ws + 81920);
    unsigned int* donecnt = (unsigned int*)(ws + 81928);
    float*        out     = (float*)d_out;

    k_prep<<<1, 1024, 0, stream>>>(labels, counts, offs, cursor, scal, donecnt);

    int waves = BATCH + NCLS;
    k_rownorm<<<(waves + 3) / 4, 256, 0, stream>>>(x, centers, mag, cmag);

    k_scatter<<<(BATCH + 255) / 256, 256, 0, stream>>>(labels, cursor, idx);

    k_fused<<<TOTAL_BLKS, 256, 0, stream>>>(x, centers, mag, cmag,
                                            counts, offs, idx, scal, donecnt, out);
}

// Round 4
// 151.336 us; speedup vs baseline: 1.3661x; 1.0369x over previous
//
#include <hip/hip_runtime.h>
#include <math.h>

#define BATCH 8192
#define FEAT  256
#define NCLS  1000

#define NGEMM  256                 // 16x16 grid of 64x64 inter tiles
#define NPAIRB 1024                // 4 waves/block; wave g owns rows (g, 8191-g)
#define NBLK   (NGEMM + NPAIRB)    // 1280 = 5 blocks/CU * 256 CU

// ws (u32): [0]=intra max bits (memset 0), [1]=done counter (memset 0),
//           [2]=inter min bits (memset 0xFF -> uint max)

__global__ __launch_bounds__(256) void k_all(const float* __restrict__ x,
                                             const int* __restrict__ labels,
                                             const float* __restrict__ centers,
                                             unsigned int* __restrict__ scal,
                                             float* __restrict__ out) {
    __shared__ __align__(16) char raw[32768];
    int t = threadIdx.x;
    int lane = t & 63, w = t >> 6;

    if (blockIdx.x < NGEMM) {
        // ---------------- inter: 64x64 f32 tile, 4x4 register blocking ----
        float (*As)[68]  = reinterpret_cast<float(*)[68]>(raw);
        float (*Bs)[68]  = reinterpret_cast<float(*)[68]>(raw + 32 * 68 * 4);
        float* cmagS     = reinterpret_cast<float*>(raw + 2 * 32 * 68 * 4); // 17408, 16B-aligned
        int bi = blockIdx.x >> 4, bj = blockIdx.x & 15;
        int i0 = bi * 64, j0 = bj * 64;

        // inline cmag for this tile's j-rows (bit-exact rownorm tree)
        for (int q = w; q < 64; q += 4) {
            int gj = j0 + q;
            float s = 0.0f;
            if (gj < NCLS) {
                float4 v = reinterpret_cast<const float4*>(centers + (size_t)gj * FEAT)[lane];
                s = v.x * v.x + v.y * v.y + v.z * v.z + v.w * v.w;
                #pragma unroll
                for (int o = 32; o > 0; o >>= 1) s += __shfl_xor(s, o);
            }
            if (lane == 0) cmagS[q] = 2.0f * s;
        }
        // (k-loop barriers below order cmagS writes before the epilogue reads)

        int tx = t & 15, ty = t >> 4;
        float acc[4][4] = {{0.f}};
        for (int kk = 0; kk < FEAT; kk += 32) {
            #pragma unroll
            for (int e = t; e < 512; e += 256) {
                int row = e >> 3, q = e & 7;
                int col = kk + q * 4;
                int gi = i0 + row, gj = j0 + row;
                float4 av = (gi < NCLS)
                    ? *reinterpret_cast<const float4*>(centers + (size_t)gi * FEAT + col)
                    : make_float4(0.f, 0.f, 0.f, 0.f);
                float4 bv = (gj < NCLS)
                    ? *reinterpret_cast<const float4*>(centers + (size_t)gj * FEAT + col)
                    : make_float4(0.f, 0.f, 0.f, 0.f);
                As[q * 4 + 0][row] = av.x; As[q * 4 + 1][row] = av.y;
                As[q * 4 + 2][row] = av.z; As[q * 4 + 3][row] = av.w;
                Bs[q * 4 + 0][row] = bv.x; Bs[q * 4 + 1][row] = bv.y;
                Bs[q * 4 + 2][row] = bv.z; Bs[q * 4 + 3][row] = bv.w;
            }
            __syncthreads();
            #pragma unroll
            for (int k = 0; k < 32; ++k) {   // sequential k: same rounding as before
                float4 a4 = *reinterpret_cast<float4*>(&As[k][ty * 4]);
                float4 b4 = *reinterpret_cast<float4*>(&Bs[k][tx * 4]);
                acc[0][0] += a4.x * b4.x; acc[0][1] += a4.x * b4.y;
                acc[0][2] += a4.x * b4.z; acc[0][3] += a4.x * b4.w;
                acc[1][0] += a4.y * b4.x; acc[1][1] += a4.y * b4.y;
                acc[1][2] += a4.y * b4.z; acc[1][3] += a4.y * b4.w;
                acc[2][0] += a4.z * b4.x; acc[2][1] += a4.z * b4.y;
                acc[2][2] += a4.z * b4.z; acc[2][3] += a4.z * b4.w;
                acc[3][0] += a4.w * b4.x; acc[3][1] += a4.w * b4.y;
                acc[3][2] += a4.w * b4.z; acc[3][3] += a4.w * b4.w;
            }
            __syncthreads();
        }
        float lmin = 1e30f;
        #pragma unroll
        for (int jj = 0; jj < 4; ++jj) {
            int j = j0 + tx * 4 + jj;
            if (j < NCLS) {
                float cm = cmagS[tx * 4 + jj];
                #pragma unroll
                for (int ii = 0; ii < 4; ++ii) {
                    int i = i0 + ty * 4 + ii;
                    if (i < NCLS) {
                        float v = cm - 2.0f * acc[ii][jj];
                        v = fminf(fmaxf(v, 1e-12f), 1e12f);
                        lmin = fminf(lmin, v);
                    }
                }
            }
        }
        #pragma unroll
        for (int o = 32; o > 0; o >>= 1) lmin = fminf(lmin, __shfl_xor(lmin, o));
        if ((t & 63) == 0) atomicMin(scal + 2, __float_as_uint(lmin));
    } else {
        // ---------------- intra: label-scan pair enumeration -------------
        int* labS = reinterpret_cast<int*>(raw);
        for (int e = t; e < BATCH; e += 256) labS[e] = labels[e];
        __syncthreads();

        int gw = (blockIdx.x - NGEMM) * 4 + w;          // 0..4095
        float vmax = 0.0f;
        #pragma unroll
        for (int half = 0; half < 2; ++half) {
            int i = half ? (BATCH - 1 - gw) : gw;       // triangle-balanced row pair
            int li = labS[i];
            float4 xa = reinterpret_cast<const float4*>(x + (size_t)i * FEAT)[lane];
            float magi = xa.x * xa.x + xa.y * xa.y + xa.z * xa.z + xa.w * xa.w;
            #pragma unroll
            for (int o = 32; o > 0; o >>= 1) magi += __shfl_xor(magi, o);

            for (int j0 = ((i + 1) >> 8) << 8; j0 < BATCH; j0 += 256) {
                int4 lv = *reinterpret_cast<const int4*>(&labS[j0 + lane * 4]);
                bool m = (lv.x == li) | (lv.y == li) | (lv.z == li) | (lv.w == li);
                unsigned long long bal = __ballot(m);
                while (bal) {
                    int lam = __builtin_ctzll(bal); bal &= bal - 1;
                    int base = j0 + (lam << 2);
                    #pragma unroll
                    for (int s4 = 0; s4 < 4; ++s4) {
                        int jj = base + s4;              // wave-uniform candidate
                        if (jj > i && labS[jj] == li) {
                            float4 xb = reinterpret_cast<const float4*>(x + (size_t)jj * FEAT)[lane];
                            float s  = xa.x * xb.x + xa.y * xb.y + xa.z * xb.z + xa.w * xb.w;
                            float mj = xb.x * xb.x + xb.y * xb.y + xb.z * xb.z + xb.w * xb.w;
                            #pragma unroll
                            for (int o = 32; o > 0; o >>= 1) {
                                s  += __shfl_xor(s, o);
                                mj += __shfl_xor(mj, o);
                            }
                            float d2 = magi + mj - 2.0f * s;   // add commutes: bit-same as ref
                            float d  = sqrtf(fmaxf(d2, 0.0f));
                            d = fminf(fmaxf(d, 1e-12f), 1e12f);
                            vmax = fmaxf(vmax, d);
                        }
                    }
                }
            }
        }
        if (lane == 0 && vmax > 0.0f)
            atomicMax(scal + 0, __float_as_uint(vmax));
    }

    // ---------------- last-done block combines the scalars ----------------
    __syncthreads();
    if (threadIdx.x == 0) {
        __threadfence();
        unsigned int done = atomicAdd(scal + 1, 1u);
        if (done == NBLK - 1) {
            float M = fmaxf(__uint_as_float(atomicOr(scal + 0, 0u)), 1e-12f); // diag floor
            float r = 1.0f / M;
            float li2 = 2.0f / (r + r);                  // harmonic mean of [M,M] * 2
            float m = fminf(__uint_as_float(atomicOr(scal + 2, 0u)), 1e12f);
            float linter = fminf(fmaxf(5.0f - m, 0.0f), 1e6f);
            out[0] = li2 + linter;                       // ALPHA = BETA = 1
        }
    }
}

extern "C" void kernel_launch(void* const* d_in, const int* in_sizes, int n_in,
                              void* d_out, int out_size, void* d_ws, size_t ws_size,
                              hipStream_t stream) {
    const float* x       = (const float*)d_in[0];
    const int*   labels  = (const int*)d_in[1];
    const float* centers = (const float*)d_in[2];
    unsigned int* scal   = (unsigned int*)d_ws;
    float*        out    = (float*)d_out;

    // [0]=intra max (0), [1]=done counter (0), [2]=inter min (0xFFFFFFFF)
    hipMemsetAsync(scal, 0x00, 8, stream);
    hipMemsetAsync((char*)d_ws + 8, 0xFF, 4, stream);

    k_all<<<NBLK, 256, 0, stream>>>(x, labels, centers, scal, out);
}